// Round 3
// baseline (126.801 us; speedup 1.0000x reference)
//
#include <hip/hip_runtime.h>
#include <math.h>

#define DD 256
#define SS 64
#define BT 2048

typedef __attribute__((ext_vector_type(4))) float f32x4;
typedef __attribute__((ext_vector_type(8))) short bf16x8;
typedef __attribute__((ext_vector_type(4))) unsigned int u32x4;

__device__ inline unsigned pack_bf16(float a, float b) {
    unsigned ua = __builtin_bit_cast(unsigned, a);
    unsigned ub = __builtin_bit_cast(unsigned, b);
    ua = (ua + 0x7fffu + ((ua >> 16) & 1u)) >> 16;
    ub = (ub + 0x7fffu + ((ub >> 16) & 1u)) >> 16;
    return ua | (ub << 16);
}

// Merged BN + FC1(relu) + FC2 + S1b. grid=(64) block=(256), one slot per block.
__global__ __launch_bounds__(256) void
k_prep(const float* __restrict__ Hs, const float* __restrict__ g,
       const float* __restrict__ b, const float* __restrict__ s_w1,
       const float* __restrict__ s_b1, const float* __restrict__ s_w2,
       const float* __restrict__ s_b2, const float* __restrict__ w_w1,
       const float* __restrict__ w_b1, float* __restrict__ transHs,
       float* __restrict__ S1b) {
    __shared__ float rowA[DD], rowB[DD], rowC[DD];
    const int s = blockIdx.x, j = threadIdx.x;
    float sum = 0.f, sumsq = 0.f;
    for (int s2 = 0; s2 < SS; ++s2) {
        float v = Hs[s2 * DD + j];
        sum += v; sumsq += v * v;
    }
    float mu  = sum * (1.f / SS);
    float var = sumsq * (1.f / SS) - mu * mu;
    rowA[j] = (Hs[s * DD + j] - mu) * rsqrtf(var + 1e-5f) * g[j] + b[j];
    __syncthreads();
    float a1 = s_b1[j];
#pragma unroll 4
    for (int d = 0; d < DD; ++d) a1 = fmaf(rowA[d], s_w1[d * DD + j], a1);
    rowB[j] = fmaxf(a1, 0.f);
    __syncthreads();
    float a2 = s_b2[j];
#pragma unroll 4
    for (int d = 0; d < DD; ++d) a2 = fmaf(rowB[d], s_w2[d * DD + j], a2);
    transHs[s * DD + j] = a2;
    rowC[j] = a2;
    __syncthreads();
    float a3 = w_b1[j];
#pragma unroll 4
    for (int d = 0; d < DD; ++d) a3 = fmaf(rowC[d], w_w1[(256 + d) * DD + j], a3);
    S1b[s * DD + j] = a3;
}

// One kernel, three pack jobs selected by blockIdx range:
//  [0,256)      Apack:  bf16(Hx) in A-fragment order
//  [256,2304)   Bs:     bf16(m_s * C) in B-fragment order, per slot
//  [2304,2336)  Xpack:  bf16(w_w1 rows 0..255) in B-fragment order
__global__ __launch_bounds__(256) void
k_pack_all(const float* __restrict__ Hx, const float* __restrict__ w_w1,
           const float* __restrict__ transHs, unsigned* __restrict__ Apack,
           unsigned* __restrict__ Xpack, unsigned* __restrict__ Bs) {
    const int bid = blockIdx.x;
    if (bid < 256) {
        int idx = bid * 256 + threadIdx.x;          // 0..65535
        int lane = idx & 63, ks = (idx >> 6) & 7, MT = idx >> 9;
        int t  = MT * 16 + (lane & 15);
        int k0 = ks * 32 + (lane >> 4) * 8;
        const float* src = Hx + t * DD + k0;
        float4 x0 = *(const float4*)src;
        float4 x1 = *(const float4*)(src + 4);
        unsigned p[4];
        p[0] = pack_bf16(x0.x, x0.y);
        p[1] = pack_bf16(x0.z, x0.w);
        p[2] = pack_bf16(x1.x, x1.y);
        p[3] = pack_bf16(x1.z, x1.w);
        *(u32x4*)(Apack + idx * 4) = *(const u32x4*)p;
    } else if (bid < 2304) {
        int b2 = bid - 256;
        int s = b2 >> 5;
        int idx = (b2 & 31) * 256 + threadIdx.x;    // 0..8191
        int lane = idx & 63, ks = (idx >> 6) & 7, nt = idx >> 9;
        int j  = nt * 16 + (lane & 15);
        int k0 = ks * 32 + (lane >> 4) * 8;
        const float* C = w_w1 + 512 * DD;
        const float* ms = transHs + s * DD;
        unsigned p[4];
#pragma unroll
        for (int e = 0; e < 4; ++e) {
            int k = k0 + 2 * e;
            p[e] = pack_bf16(ms[k] * C[k * DD + j], ms[k + 1] * C[(k + 1) * DD + j]);
        }
        *(u32x4*)(Bs + (s * 8192 + idx) * 4) = *(const u32x4*)p;
    } else {
        int idx = (bid - 2304) * 256 + threadIdx.x; // 0..8191
        int lane = idx & 63, ks = (idx >> 6) & 7, nt = idx >> 9;
        int j  = nt * 16 + (lane & 15);
        int k0 = ks * 32 + (lane >> 4) * 8;
        unsigned p[4];
#pragma unroll
        for (int e = 0; e < 4; ++e) {
            int k = k0 + 2 * e;
            p[e] = pack_bf16(w_w1[k * DD + j], w_w1[(k + 1) * DD + j]);
        }
        *(u32x4*)(Xpack + idx * 4) = *(const u32x4*)p;
    }
}

// X1 = Hx @ w_w1[0:256] via MFMA. grid=(32) block=(256).
__global__ __launch_bounds__(256) void
k_x1_mfma(const unsigned* __restrict__ Apack, const unsigned* __restrict__ Xpack,
          float* __restrict__ X1) {
    const int t0 = blockIdx.x * 64;
    const int tid = threadIdx.x;
    const int w = tid >> 6, l = tid & 63;
    const int lrow = l & 15, lg = l >> 4;
    f32x4 acc[4][4] = {};
    for (int ks = 0; ks < 8; ++ks) {
        bf16x8 af[4];
#pragma unroll
        for (int mt = 0; mt < 4; ++mt)
            af[mt] = *(const bf16x8*)(Apack + (((blockIdx.x * 4 + mt) * 8 + ks) * 64 + l) * 4);
#pragma unroll
        for (int nt = 0; nt < 4; ++nt) {
            const bf16x8 bf = *(const bf16x8*)(Xpack + (((w * 4 + nt) * 8 + ks) * 64 + l) * 4);
#pragma unroll
            for (int mt = 0; mt < 4; ++mt)
                acc[mt][nt] = __builtin_amdgcn_mfma_f32_16x16x32_bf16(af[mt], bf, acc[mt][nt], 0, 0, 0);
        }
    }
#pragma unroll
    for (int mt = 0; mt < 4; ++mt)
#pragma unroll
        for (int nt = 0; nt < 4; ++nt)
#pragma unroll
            for (int i = 0; i < 4; ++i)
                X1[(t0 + mt * 16 + lg * 4 + i) * DD + (w * 4 + nt) * 16 + lrow] = acc[mt][nt][i];
}

// atten[t][s] = w2 . relu( Apack@Bs[s] + X1[t] + S1b[s] ) + b2
// grid=(32,64) block=256. Pure streaming MFMA, no LDS staging.
__global__ __launch_bounds__(256) void
k_main_mfma(const unsigned* __restrict__ Apack, const unsigned* __restrict__ Bs,
            const float* __restrict__ X1, const float* __restrict__ S1b,
            const float* __restrict__ w2, const float* __restrict__ w_b2,
            float* __restrict__ atten) {
    __shared__ float attp[4][64];
    const int s  = blockIdx.y;
    const int t0 = blockIdx.x * 64;
    const int tid = threadIdx.x;
    const int w = tid >> 6, l = tid & 63;
    const int lrow = l & 15, lg = l >> 4;
    const unsigned* Bsl = Bs + s * 32768;

    f32x4 acc[4][4] = {};
    for (int ks = 0; ks < 8; ++ks) {
        bf16x8 af[4];
#pragma unroll
        for (int mt = 0; mt < 4; ++mt)
            af[mt] = *(const bf16x8*)(Apack + (((blockIdx.x * 4 + mt) * 8 + ks) * 64 + l) * 4);
#pragma unroll
        for (int nt = 0; nt < 4; ++nt) {
            const bf16x8 bf = *(const bf16x8*)(Bsl + (((w * 4 + nt) * 8 + ks) * 64 + l) * 4);
#pragma unroll
            for (int mt = 0; mt < 4; ++mt)
                acc[mt][nt] = __builtin_amdgcn_mfma_f32_16x16x32_bf16(af[mt], bf, acc[mt][nt], 0, 0, 0);
        }
    }

    float s1[4], w2v[4];
#pragma unroll
    for (int nt = 0; nt < 4; ++nt) {
        int jn = (w * 4 + nt) * 16 + lrow;
        s1[nt]  = S1b[s * DD + jn];
        w2v[nt] = w2[jn];
    }
#pragma unroll
    for (int mt = 0; mt < 4; ++mt) {
#pragma unroll
        for (int i = 0; i < 4; ++i) {
            const int t = t0 + mt * 16 + lg * 4 + i;
            float p = 0.f;
#pragma unroll
            for (int nt = 0; nt < 4; ++nt) {
                int jn = (w * 4 + nt) * 16 + lrow;
                float h = acc[mt][nt][i] + X1[t * DD + jn] + s1[nt];
                h = fmaxf(h, 0.f);
                p = fmaf(h, w2v[nt], p);
            }
            p += __shfl_xor(p, 1);
            p += __shfl_xor(p, 2);
            p += __shfl_xor(p, 4);
            p += __shfl_xor(p, 8);
            if (lrow == 0) attp[w][mt * 16 + lg * 4 + i] = p;
        }
    }
    __syncthreads();
    if (tid < 64) {
        float r = attp[0][tid] + attp[1][tid] + attp[2][tid] + attp[3][tid] + w_b2[0];
        atten[(t0 + tid) * SS + s] = r;
    }
}

// softmax over slots + G = score@transHs + output assembly. grid=(512) block=(256)
__global__ __launch_bounds__(256) void
k_out(const float* __restrict__ Hx, const float* __restrict__ m,
      const float* __restrict__ atten, float* __restrict__ outU,
      float* __restrict__ outA) {
    int wave = threadIdx.x >> 6, lane = threadIdx.x & 63;
    int t = blockIdx.x * 4 + wave;
    float a = atten[t * SS + lane];
    float mx = a;
#pragma unroll
    for (int off = 32; off; off >>= 1) mx = fmaxf(mx, __shfl_xor(mx, off));
    float e = __expf(a - mx);
    float sum = e;
#pragma unroll
    for (int off = 32; off; off >>= 1) sum += __shfl_xor(sum, off);
    float p = e / sum;
    outA[t * SS + lane] = p;
    float gacc[4] = {};
    for (int s = 0; s < SS; ++s) {
        float ps = __shfl(p, s);
#pragma unroll
        for (int q = 0; q < 4; ++q)
            gacc[q] = fmaf(ps, m[s * DD + lane + 64 * q], gacc[q]);
    }
#pragma unroll
    for (int q = 0; q < 4; ++q) {
        int j = lane + 64 * q;
        float x = Hx[t * DD + j];
        outU[t * 2 * DD + j] = x;
        outU[t * 2 * DD + DD + j] = x + gacc[q];
    }
}

extern "C" void kernel_launch(void* const* d_in, const int* in_sizes, int n_in,
                              void* d_out, int out_size, void* d_ws, size_t ws_size,
                              hipStream_t stream) {
    const float* Hx   = (const float*)d_in[0];
    const float* Hs   = (const float*)d_in[1];
    const float* bn_g = (const float*)d_in[2];
    const float* bn_b = (const float*)d_in[3];
    const float* s_w1 = (const float*)d_in[4];
    const float* s_b1 = (const float*)d_in[5];
    const float* s_w2 = (const float*)d_in[6];
    const float* s_b2 = (const float*)d_in[7];
    const float* w_w1 = (const float*)d_in[8];
    const float* w_b1 = (const float*)d_in[9];
    const float* w_w2 = (const float*)d_in[10];
    const float* w_b2 = (const float*)d_in[11];

    float* ws      = (float*)d_ws;
    float* transHs = ws;                        // 16384 f
    float* S1b     = ws + 16384;                // 16384 f
    float* X1      = ws + 32768;                // 524288 f
    float* atten   = ws + 557056;               // 131072 f
    unsigned* Apack = (unsigned*)(ws + 688128); // 262144 u32 (1 MB)
    unsigned* Xpack = Apack + 262144;           // 32768 u32 (128 KB)
    unsigned* Bs    = Xpack + 32768;            // 2097152 u32 (8 MB)

    float* outU = (float*)d_out;                // [2048][512]
    float* outA = outU + BT * 2 * DD;           // [2048][64]

    k_prep<<<SS, 256, 0, stream>>>(Hs, bn_g, bn_b, s_w1, s_b1, s_w2, s_b2,
                                   w_w1, w_b1, transHs, S1b);
    k_pack_all<<<2336, 256, 0, stream>>>(Hx, w_w1, transHs, Apack, Xpack, Bs);
    k_x1_mfma<<<32, 256, 0, stream>>>(Apack, Xpack, X1);
    dim3 gmain(BT / 64, SS);
    k_main_mfma<<<gmain, 256, 0, stream>>>(Apack, Bs, X1, S1b, w_w2, w_b2, atten);
    k_out<<<BT / 4, 256, 0, stream>>>(Hx, transHs, atten, outU, outA);
}

// Round 4
// 91.758 us; speedup vs baseline: 1.3819x; 1.3819x over previous
//
#include <hip/hip_runtime.h>
#include <math.h>

#define DD 256
#define SS 64
#define BT 2048

typedef __attribute__((ext_vector_type(4))) float f32x4;
typedef __attribute__((ext_vector_type(8))) short bf16x8;
typedef __attribute__((ext_vector_type(4))) unsigned int u32x4;

__device__ inline unsigned pack_bf16(float a, float b) {
    unsigned ua = __builtin_bit_cast(unsigned, a);
    unsigned ub = __builtin_bit_cast(unsigned, b);
    ua = (ua + 0x7fffu + ((ua >> 16) & 1u)) >> 16;
    ub = (ub + 0x7fffu + ((ub >> 16) & 1u)) >> 16;
    return ua | (ub << 16);
}

// BN over slot dim. grid=(64) block=(256): block s, thread j. Stats computed
// redundantly per block (coalesced across j, L2-resident).
__global__ __launch_bounds__(256) void
k_bn2(const float* __restrict__ Hs, const float* __restrict__ g,
      const float* __restrict__ b, float* __restrict__ hs) {
    const int s = blockIdx.x, j = threadIdx.x;
    float sum = 0.f, sumsq = 0.f;
#pragma unroll 16
    for (int s2 = 0; s2 < SS; ++s2) {
        float v = Hs[s2 * DD + j];
        sum += v; sumsq += v * v;
    }
    float mu  = sum * (1.f / SS);
    float var = sumsq * (1.f / SS) - mu * mu;
    hs[s * DD + j] = (Hs[s * DD + j] - mu) * rsqrtf(var + 1e-5f) * g[j] + b[j];
}

// out[s][j] = act(sum_d in[s][d] W[d][j] + bias[j]); K split over 4 waves.
// grid=(64*4) block=(256): block = (slot, j-quarter).
template <bool RELU>
__global__ __launch_bounds__(256) void
k_fc(const float* __restrict__ in, const float* __restrict__ W,
     const float* __restrict__ bias, float* __restrict__ out) {
    __shared__ float rowA[DD];
    __shared__ float red[4][64];
    const int s = blockIdx.x >> 2, q = blockIdx.x & 3;
    const int tid = threadIdx.x;
    rowA[tid] = in[s * DD + tid];
    __syncthreads();
    const int jj = tid & 63, kw = tid >> 6;
    const int j = q * 64 + jj;
    float acc = 0.f;
#pragma unroll 16
    for (int d = kw * 64; d < kw * 64 + 64; ++d)
        acc = fmaf(rowA[d], W[d * DD + j], acc);
    red[kw][jj] = acc;
    __syncthreads();
    if (tid < 64) {
        float r = red[0][tid] + red[1][tid] + red[2][tid] + red[3][tid] + bias[q * 64 + tid];
        if (RELU) r = fmaxf(r, 0.f);
        out[s * DD + q * 64 + tid] = r;
    }
}

// One kernel, three pack jobs selected by blockIdx range:
//  [0,256)      Apack:  bf16(Hx) in A-fragment order
//  [256,2304)   Bs:     bf16(m_s * C) in B-fragment order, per slot
//  [2304,2336)  Xpack:  bf16(w_w1 rows 0..255) in B-fragment order
__global__ __launch_bounds__(256) void
k_pack_all(const float* __restrict__ Hx, const float* __restrict__ w_w1,
           const float* __restrict__ transHs, unsigned* __restrict__ Apack,
           unsigned* __restrict__ Xpack, unsigned* __restrict__ Bs) {
    const int bid = blockIdx.x;
    if (bid < 256) {
        int idx = bid * 256 + threadIdx.x;          // 0..65535
        int lane = idx & 63, ks = (idx >> 6) & 7, MT = idx >> 9;
        int t  = MT * 16 + (lane & 15);
        int k0 = ks * 32 + (lane >> 4) * 8;
        const float* src = Hx + t * DD + k0;
        float4 x0 = *(const float4*)src;
        float4 x1 = *(const float4*)(src + 4);
        unsigned p[4];
        p[0] = pack_bf16(x0.x, x0.y);
        p[1] = pack_bf16(x0.z, x0.w);
        p[2] = pack_bf16(x1.x, x1.y);
        p[3] = pack_bf16(x1.z, x1.w);
        *(u32x4*)(Apack + idx * 4) = *(const u32x4*)p;
    } else if (bid < 2304) {
        int b2 = bid - 256;
        int s = b2 >> 5;
        int idx = (b2 & 31) * 256 + threadIdx.x;    // 0..8191
        int lane = idx & 63, ks = (idx >> 6) & 7, nt = idx >> 9;
        int j  = nt * 16 + (lane & 15);
        int k0 = ks * 32 + (lane >> 4) * 8;
        const float* C = w_w1 + 512 * DD;
        const float* ms = transHs + s * DD;
        unsigned p[4];
#pragma unroll
        for (int e = 0; e < 4; ++e) {
            int k = k0 + 2 * e;
            p[e] = pack_bf16(ms[k] * C[k * DD + j], ms[k + 1] * C[(k + 1) * DD + j]);
        }
        *(u32x4*)(Bs + (s * 8192 + idx) * 4) = *(const u32x4*)p;
    } else {
        int idx = (bid - 2304) * 256 + threadIdx.x; // 0..8191
        int lane = idx & 63, ks = (idx >> 6) & 7, nt = idx >> 9;
        int j  = nt * 16 + (lane & 15);
        int k0 = ks * 32 + (lane >> 4) * 8;
        unsigned p[4];
#pragma unroll
        for (int e = 0; e < 4; ++e) {
            int k = k0 + 2 * e;
            p[e] = pack_bf16(w_w1[k * DD + j], w_w1[(k + 1) * DD + j]);
        }
        *(u32x4*)(Xpack + idx * 4) = *(const u32x4*)p;
    }
}

// X1 = Hx @ w_w1[0:256] via MFMA. grid=(32) block=(256).
__global__ __launch_bounds__(256) void
k_x1_mfma(const unsigned* __restrict__ Apack, const unsigned* __restrict__ Xpack,
          float* __restrict__ X1) {
    const int t0 = blockIdx.x * 64;
    const int tid = threadIdx.x;
    const int w = tid >> 6, l = tid & 63;
    const int lrow = l & 15, lg = l >> 4;
    f32x4 acc[4][4] = {};
    for (int ks = 0; ks < 8; ++ks) {
        bf16x8 af[4];
#pragma unroll
        for (int mt = 0; mt < 4; ++mt)
            af[mt] = *(const bf16x8*)(Apack + (((blockIdx.x * 4 + mt) * 8 + ks) * 64 + l) * 4);
#pragma unroll
        for (int nt = 0; nt < 4; ++nt) {
            const bf16x8 bf = *(const bf16x8*)(Xpack + (((w * 4 + nt) * 8 + ks) * 64 + l) * 4);
#pragma unroll
            for (int mt = 0; mt < 4; ++mt)
                acc[mt][nt] = __builtin_amdgcn_mfma_f32_16x16x32_bf16(af[mt], bf, acc[mt][nt], 0, 0, 0);
        }
    }
#pragma unroll
    for (int mt = 0; mt < 4; ++mt)
#pragma unroll
        for (int nt = 0; nt < 4; ++nt)
#pragma unroll
            for (int i = 0; i < 4; ++i)
                X1[(t0 + mt * 16 + lg * 4 + i) * DD + (w * 4 + nt) * 16 + lrow] = acc[mt][nt][i];
}

// atten[t][s] = w2 . relu( Apack@Bs[s] + X1[t] + S1b[s] ) + b2
// grid=(32,64) block=256. Pure streaming MFMA, no LDS staging.
__global__ __launch_bounds__(256) void
k_main_mfma(const unsigned* __restrict__ Apack, const unsigned* __restrict__ Bs,
            const float* __restrict__ X1, const float* __restrict__ S1b,
            const float* __restrict__ w2, const float* __restrict__ w_b2,
            float* __restrict__ atten) {
    __shared__ float attp[4][64];
    const int s  = blockIdx.y;
    const int t0 = blockIdx.x * 64;
    const int tid = threadIdx.x;
    const int w = tid >> 6, l = tid & 63;
    const int lrow = l & 15, lg = l >> 4;
    const unsigned* Bsl = Bs + s * 32768;

    f32x4 acc[4][4] = {};
    for (int ks = 0; ks < 8; ++ks) {
        bf16x8 af[4];
#pragma unroll
        for (int mt = 0; mt < 4; ++mt)
            af[mt] = *(const bf16x8*)(Apack + (((blockIdx.x * 4 + mt) * 8 + ks) * 64 + l) * 4);
#pragma unroll
        for (int nt = 0; nt < 4; ++nt) {
            const bf16x8 bf = *(const bf16x8*)(Bsl + (((w * 4 + nt) * 8 + ks) * 64 + l) * 4);
#pragma unroll
            for (int mt = 0; mt < 4; ++mt)
                acc[mt][nt] = __builtin_amdgcn_mfma_f32_16x16x32_bf16(af[mt], bf, acc[mt][nt], 0, 0, 0);
        }
    }

    float s1[4], w2v[4];
#pragma unroll
    for (int nt = 0; nt < 4; ++nt) {
        int jn = (w * 4 + nt) * 16 + lrow;
        s1[nt]  = S1b[s * DD + jn];
        w2v[nt] = w2[jn];
    }
#pragma unroll
    for (int mt = 0; mt < 4; ++mt) {
#pragma unroll
        for (int i = 0; i < 4; ++i) {
            const int t = t0 + mt * 16 + lg * 4 + i;
            float p = 0.f;
#pragma unroll
            for (int nt = 0; nt < 4; ++nt) {
                int jn = (w * 4 + nt) * 16 + lrow;
                float h = acc[mt][nt][i] + X1[t * DD + jn] + s1[nt];
                h = fmaxf(h, 0.f);
                p = fmaf(h, w2v[nt], p);
            }
            p += __shfl_xor(p, 1);
            p += __shfl_xor(p, 2);
            p += __shfl_xor(p, 4);
            p += __shfl_xor(p, 8);
            if (lrow == 0) attp[w][mt * 16 + lg * 4 + i] = p;
        }
    }
    __syncthreads();
    if (tid < 64) {
        float r = attp[0][tid] + attp[1][tid] + attp[2][tid] + attp[3][tid] + w_b2[0];
        atten[(t0 + tid) * SS + s] = r;
    }
}

// softmax over slots + G = score@transHs + output assembly. grid=(512) block=(256)
__global__ __launch_bounds__(256) void
k_out(const float* __restrict__ Hx, const float* __restrict__ m,
      const float* __restrict__ atten, float* __restrict__ outU,
      float* __restrict__ outA) {
    int wave = threadIdx.x >> 6, lane = threadIdx.x & 63;
    int t = blockIdx.x * 4 + wave;
    float a = atten[t * SS + lane];
    float mx = a;
#pragma unroll
    for (int off = 32; off; off >>= 1) mx = fmaxf(mx, __shfl_xor(mx, off));
    float e = __expf(a - mx);
    float sum = e;
#pragma unroll
    for (int off = 32; off; off >>= 1) sum += __shfl_xor(sum, off);
    float p = e / sum;
    outA[t * SS + lane] = p;
    float gacc[4] = {};
    for (int s = 0; s < SS; ++s) {
        float ps = __shfl(p, s);
#pragma unroll
        for (int q = 0; q < 4; ++q)
            gacc[q] = fmaf(ps, m[s * DD + lane + 64 * q], gacc[q]);
    }
#pragma unroll
    for (int q = 0; q < 4; ++q) {
        int j = lane + 64 * q;
        float x = Hx[t * DD + j];
        outU[t * 2 * DD + j] = x;
        outU[t * 2 * DD + DD + j] = x + gacc[q];
    }
}

extern "C" void kernel_launch(void* const* d_in, const int* in_sizes, int n_in,
                              void* d_out, int out_size, void* d_ws, size_t ws_size,
                              hipStream_t stream) {
    const float* Hx   = (const float*)d_in[0];
    const float* Hs   = (const float*)d_in[1];
    const float* bn_g = (const float*)d_in[2];
    const float* bn_b = (const float*)d_in[3];
    const float* s_w1 = (const float*)d_in[4];
    const float* s_b1 = (const float*)d_in[5];
    const float* s_w2 = (const float*)d_in[6];
    const float* s_b2 = (const float*)d_in[7];
    const float* w_w1 = (const float*)d_in[8];
    const float* w_b1 = (const float*)d_in[9];
    const float* w_w2 = (const float*)d_in[10];
    const float* w_b2 = (const float*)d_in[11];

    float* ws      = (float*)d_ws;
    float* transHs = ws;                        // 16384 f
    float* S1b     = ws + 16384;                // 16384 f
    float* t1      = ws + 32768;                // 16384 f
    float* hs      = ws + 49152;                // 16384 f
    float* X1      = ws + 65536;                // 524288 f
    float* atten   = ws + 589824;               // 131072 f
    unsigned* Apack = (unsigned*)(ws + 720896); // 262144 u32 (1 MB)
    unsigned* Xpack = Apack + 262144;           // 32768 u32 (128 KB)
    unsigned* Bs    = Xpack + 32768;            // 2097152 u32 (8 MB)

    float* outU = (float*)d_out;                // [2048][512]
    float* outA = outU + BT * 2 * DD;           // [2048][64]

    k_bn2<<<SS, 256, 0, stream>>>(Hs, bn_g, bn_b, hs);
    k_fc<true ><<<SS * 4, 256, 0, stream>>>(hs, s_w1, s_b1, t1);
    k_fc<false><<<SS * 4, 256, 0, stream>>>(t1, s_w2, s_b2, transHs);
    k_fc<false><<<SS * 4, 256, 0, stream>>>(transHs, w_w1 + 256 * DD, w_b1, S1b);
    k_pack_all<<<2336, 256, 0, stream>>>(Hx, w_w1, transHs, Apack, Xpack, Bs);
    k_x1_mfma<<<32, 256, 0, stream>>>(Apack, Xpack, X1);
    dim3 gmain(BT / 64, SS);
    k_main_mfma<<<gmain, 256, 0, stream>>>(Apack, Bs, X1, S1b, w_w2, w_b2, atten);
    k_out<<<BT / 4, 256, 0, stream>>>(Hx, transHs, atten, outU, outA);
}

// Round 5
// 68.639 us; speedup vs baseline: 1.8473x; 1.3368x over previous
//
#include <hip/hip_runtime.h>
#include <math.h>

#define DD 256
#define SS 64
#define BT 2048

typedef __attribute__((ext_vector_type(4))) float f32x4;
typedef __attribute__((ext_vector_type(8))) short bf16x8;
typedef __attribute__((ext_vector_type(4))) unsigned int u32x4;

__device__ inline unsigned pack_bf16(float a, float b) {
    unsigned ua = __builtin_bit_cast(unsigned, a);
    unsigned ub = __builtin_bit_cast(unsigned, b);
    ua = (ua + 0x7fffu + ((ua >> 16) & 1u)) >> 16;
    ub = (ub + 0x7fffu + ((ub >> 16) & 1u)) >> 16;
    return ua | (ub << 16);
}

// BN over slot dim. grid=(64) block=(256).
__global__ __launch_bounds__(256) void
k_bn2(const float* __restrict__ Hs, const float* __restrict__ g,
      const float* __restrict__ b, float* __restrict__ hs) {
    const int s = blockIdx.x, j = threadIdx.x;
    float sum = 0.f, sumsq = 0.f;
#pragma unroll 16
    for (int s2 = 0; s2 < SS; ++s2) {
        float v = Hs[s2 * DD + j];
        sum += v; sumsq += v * v;
    }
    float mu  = sum * (1.f / SS);
    float var = sumsq * (1.f / SS) - mu * mu;
    hs[s * DD + j] = (Hs[s * DD + j] - mu) * rsqrtf(var + 1e-5f) * g[j] + b[j];
}

// out[s][j] = act(sum_d in[s][d] W[d][j] + bias[j]); K split over 4 waves.
// grid=(64*4) block=(256): block = (slot, j-quarter).
template <bool RELU>
__global__ __launch_bounds__(256) void
k_fc(const float* __restrict__ in, const float* __restrict__ W,
     const float* __restrict__ bias, float* __restrict__ out) {
    __shared__ float rowA[DD];
    __shared__ float red[4][64];
    const int s = blockIdx.x >> 2, q = blockIdx.x & 3;
    const int tid = threadIdx.x;
    rowA[tid] = in[s * DD + tid];
    __syncthreads();
    const int jj = tid & 63, kw = tid >> 6;
    const int j = q * 64 + jj;
    float acc = 0.f;
#pragma unroll 16
    for (int d = kw * 64; d < kw * 64 + 64; ++d)
        acc = fmaf(rowA[d], W[d * DD + j], acc);
    red[kw][jj] = acc;
    __syncthreads();
    if (tid < 64) {
        float r = red[0][tid] + red[1][tid] + red[2][tid] + red[3][tid] + bias[q * 64 + tid];
        if (RELU) r = fmaxf(r, 0.f);
        out[s * DD + q * 64 + tid] = r;
    }
}

// Two pack jobs:
//  [0,256)    Apack: bf16(Hx) in A-fragment order
//  [256,2304) Bs:    bf16(W1a + m_s*C) in B-fragment order, per slot
//             (W1a = w_w1 rows 0..255 folds the X1 term into this GEMM)
__global__ __launch_bounds__(256) void
k_pack_all(const float* __restrict__ Hx, const float* __restrict__ w_w1,
           const float* __restrict__ transHs, unsigned* __restrict__ Apack,
           unsigned* __restrict__ Bs) {
    const int bid = blockIdx.x;
    if (bid < 256) {
        int idx = bid * 256 + threadIdx.x;          // 0..65535
        int lane = idx & 63, ks = (idx >> 6) & 7, MT = idx >> 9;
        int t  = MT * 16 + (lane & 15);
        int k0 = ks * 32 + (lane >> 4) * 8;
        const float* src = Hx + t * DD + k0;
        float4 x0 = *(const float4*)src;
        float4 x1 = *(const float4*)(src + 4);
        unsigned p[4];
        p[0] = pack_bf16(x0.x, x0.y);
        p[1] = pack_bf16(x0.z, x0.w);
        p[2] = pack_bf16(x1.x, x1.y);
        p[3] = pack_bf16(x1.z, x1.w);
        *(u32x4*)(Apack + idx * 4) = *(const u32x4*)p;
    } else {
        int b2 = bid - 256;
        int s = b2 >> 5;
        int idx = (b2 & 31) * 256 + threadIdx.x;    // 0..8191
        int lane = idx & 63, ks = (idx >> 6) & 7, nt = idx >> 9;
        int j  = nt * 16 + (lane & 15);
        int k0 = ks * 32 + (lane >> 4) * 8;
        const float* C   = w_w1 + 512 * DD;
        const float* W1a = w_w1;
        const float* ms  = transHs + s * DD;
        unsigned p[4];
#pragma unroll
        for (int e = 0; e < 4; ++e) {
            int k = k0 + 2 * e;
            float f0 = W1a[k * DD + j] + ms[k] * C[k * DD + j];
            float f1 = W1a[(k + 1) * DD + j] + ms[k + 1] * C[(k + 1) * DD + j];
            p[e] = pack_bf16(f0, f1);
        }
        *(u32x4*)(Bs + (s * 8192 + idx) * 4) = *(const u32x4*)p;
    }
}

// atten[t][s] = w2 . relu( Apack@Bs[s] + S1b[s] ) + b2
// grid=(16,64) block=256: 128 tokens x 256 j per block. Pure streaming MFMA.
__global__ __launch_bounds__(256, 2) void
k_main_mfma(const unsigned* __restrict__ Apack, const unsigned* __restrict__ Bs,
            const float* __restrict__ S1b, const float* __restrict__ w2,
            const float* __restrict__ w_b2, float* __restrict__ atten) {
    __shared__ float attp[4][128];
    const int s  = blockIdx.y;
    const int t0 = blockIdx.x * 128;
    const int tid = threadIdx.x;
    const int w = tid >> 6, l = tid & 63;
    const int lrow = l & 15, lg = l >> 4;
    const unsigned* Bsl = Bs + s * 32768;

    f32x4 acc[8][4] = {};
    for (int ks = 0; ks < 8; ++ks) {
        bf16x8 af[8];
#pragma unroll
        for (int mt = 0; mt < 8; ++mt)
            af[mt] = *(const bf16x8*)(Apack + (((blockIdx.x * 8 + mt) * 8 + ks) * 64 + l) * 4);
#pragma unroll
        for (int nt = 0; nt < 4; ++nt) {
            const bf16x8 bf = *(const bf16x8*)(Bsl + (((w * 4 + nt) * 8 + ks) * 64 + l) * 4);
#pragma unroll
            for (int mt = 0; mt < 8; ++mt)
                acc[mt][nt] = __builtin_amdgcn_mfma_f32_16x16x32_bf16(af[mt], bf, acc[mt][nt], 0, 0, 0);
        }
    }

    float s1[4], w2v[4];
#pragma unroll
    for (int nt = 0; nt < 4; ++nt) {
        int jn = (w * 4 + nt) * 16 + lrow;
        s1[nt]  = S1b[s * DD + jn];
        w2v[nt] = w2[jn];
    }
#pragma unroll
    for (int mt = 0; mt < 8; ++mt) {
#pragma unroll
        for (int i = 0; i < 4; ++i) {
            float p = 0.f;
#pragma unroll
            for (int nt = 0; nt < 4; ++nt) {
                float h = fmaxf(acc[mt][nt][i] + s1[nt], 0.f);
                p = fmaf(h, w2v[nt], p);
            }
            p += __shfl_xor(p, 1);
            p += __shfl_xor(p, 2);
            p += __shfl_xor(p, 4);
            p += __shfl_xor(p, 8);
            if (lrow == 0) attp[w][mt * 16 + lg * 4 + i] = p;
        }
    }
    __syncthreads();
    if (tid < 128) {
        float r = attp[0][tid] + attp[1][tid] + attp[2][tid] + attp[3][tid] + w_b2[0];
        atten[(t0 + tid) * SS + s] = r;
    }
}

// softmax over slots + G = score@transHs + output assembly. grid=(512) block=(256)
__global__ __launch_bounds__(256) void
k_out(const float* __restrict__ Hx, const float* __restrict__ m,
      const float* __restrict__ atten, float* __restrict__ outU,
      float* __restrict__ outA) {
    int wave = threadIdx.x >> 6, lane = threadIdx.x & 63;
    int t = blockIdx.x * 4 + wave;
    float a = atten[t * SS + lane];
    float mx = a;
#pragma unroll
    for (int off = 32; off; off >>= 1) mx = fmaxf(mx, __shfl_xor(mx, off));
    float e = __expf(a - mx);
    float sum = e;
#pragma unroll
    for (int off = 32; off; off >>= 1) sum += __shfl_xor(sum, off);
    float p = e / sum;
    outA[t * SS + lane] = p;
    float gacc[4] = {};
    for (int s = 0; s < SS; ++s) {
        float ps = __shfl(p, s);
#pragma unroll
        for (int q = 0; q < 4; ++q)
            gacc[q] = fmaf(ps, m[s * DD + lane + 64 * q], gacc[q]);
    }
#pragma unroll
    for (int q = 0; q < 4; ++q) {
        int j = lane + 64 * q;
        float x = Hx[t * DD + j];
        outU[t * 2 * DD + j] = x;
        outU[t * 2 * DD + DD + j] = x + gacc[q];
    }
}

extern "C" void kernel_launch(void* const* d_in, const int* in_sizes, int n_in,
                              void* d_out, int out_size, void* d_ws, size_t ws_size,
                              hipStream_t stream) {
    const float* Hx   = (const float*)d_in[0];
    const float* Hs   = (const float*)d_in[1];
    const float* bn_g = (const float*)d_in[2];
    const float* bn_b = (const float*)d_in[3];
    const float* s_w1 = (const float*)d_in[4];
    const float* s_b1 = (const float*)d_in[5];
    const float* s_w2 = (const float*)d_in[6];
    const float* s_b2 = (const float*)d_in[7];
    const float* w_w1 = (const float*)d_in[8];
    const float* w_b1 = (const float*)d_in[9];
    const float* w_w2 = (const float*)d_in[10];
    const float* w_b2 = (const float*)d_in[11];

    float* ws      = (float*)d_ws;
    float* transHs = ws;                        // 16384 f
    float* S1b     = ws + 16384;                // 16384 f
    float* t1      = ws + 32768;                // 16384 f
    float* hs      = ws + 49152;                // 16384 f
    float* atten   = ws + 65536;                // 131072 f
    unsigned* Apack = (unsigned*)(ws + 196608); // 262144 u32 (1 MB)
    unsigned* Bs    = Apack + 262144;           // 2097152 u32 (8 MB)

    float* outU = (float*)d_out;                // [2048][512]
    float* outA = outU + BT * 2 * DD;           // [2048][64]

    k_bn2<<<SS, 256, 0, stream>>>(Hs, bn_g, bn_b, hs);
    k_fc<true ><<<SS * 4, 256, 0, stream>>>(hs, s_w1, s_b1, t1);
    k_fc<false><<<SS * 4, 256, 0, stream>>>(t1, s_w2, s_b2, transHs);
    k_fc<false><<<SS * 4, 256, 0, stream>>>(transHs, w_w1 + 256 * DD, w_b1, S1b);
    k_pack_all<<<2304, 256, 0, stream>>>(Hx, w_w1, transHs, Apack, Bs);
    dim3 gmain(BT / 128, SS);
    k_main_mfma<<<gmain, 256, 0, stream>>>(Apack, Bs, S1b, w_w2, w_b2, atten);
    k_out<<<BT / 4, 256, 0, stream>>>(Hx, transHs, atten, outU, outA);
}

// Round 6
// 61.130 us; speedup vs baseline: 2.0743x; 1.1228x over previous
//
#include <hip/hip_runtime.h>
#include <math.h>

#define DD 256
#define SS 64
#define BT 2048

typedef __attribute__((ext_vector_type(4))) float f32x4;
typedef __attribute__((ext_vector_type(8))) short bf16x8;
typedef __attribute__((ext_vector_type(4))) unsigned int u32x4;

typedef __attribute__((address_space(3))) unsigned lds_u32;
typedef const __attribute__((address_space(1))) unsigned glb_u32;

__device__ inline unsigned pack_bf16(float a, float b) {
    unsigned ua = __builtin_bit_cast(unsigned, a);
    unsigned ub = __builtin_bit_cast(unsigned, b);
    ua = (ua + 0x7fffu + ((ua >> 16) & 1u)) >> 16;
    ub = (ub + 0x7fffu + ((ub >> 16) & 1u)) >> 16;
    return ua | (ub << 16);
}

// Fused BN + FC1(relu) + FC2 + S1b. grid=(64) block=(1024): block = slot,
// thread = (j, k-quarter). Chain lives in LDS; 3 launches + round-trips saved.
__global__ __launch_bounds__(1024) void
k_prep2(const float* __restrict__ Hs, const float* __restrict__ g,
        const float* __restrict__ b, const float* __restrict__ s_w1,
        const float* __restrict__ s_b1, const float* __restrict__ s_w2,
        const float* __restrict__ s_b2, const float* __restrict__ w_w1,
        const float* __restrict__ w_b1, float* __restrict__ transHs,
        float* __restrict__ S1b) {
    __shared__ float rowA[DD], rowB[DD], rowC[DD];
    __shared__ float red[8][DD];
    const int s = blockIdx.x;
    const int j = threadIdx.x & 255, kw = threadIdx.x >> 8;
    float sum = 0.f, sumsq = 0.f;
#pragma unroll
    for (int s2 = kw * 16; s2 < kw * 16 + 16; ++s2) {
        float v = Hs[s2 * DD + j];
        sum += v; sumsq += v * v;
    }
    red[kw][j] = sum; red[4 + kw][j] = sumsq;
    __syncthreads();
    if (kw == 0) {
        float st = red[0][j] + red[1][j] + red[2][j] + red[3][j];
        float sq = red[4][j] + red[5][j] + red[6][j] + red[7][j];
        float mu  = st * (1.f / SS);
        float var = sq * (1.f / SS) - mu * mu;
        rowA[j] = (Hs[s * DD + j] - mu) * rsqrtf(var + 1e-5f) * g[j] + b[j];
    }
    __syncthreads();
    float a1 = 0.f;
#pragma unroll 16
    for (int d = kw * 64; d < kw * 64 + 64; ++d)
        a1 = fmaf(rowA[d], s_w1[d * DD + j], a1);
    red[kw][j] = a1;
    __syncthreads();
    if (kw == 0)
        rowB[j] = fmaxf(red[0][j] + red[1][j] + red[2][j] + red[3][j] + s_b1[j], 0.f);
    __syncthreads();
    float a2 = 0.f;
#pragma unroll 16
    for (int d = kw * 64; d < kw * 64 + 64; ++d)
        a2 = fmaf(rowB[d], s_w2[d * DD + j], a2);
    red[kw][j] = a2;
    __syncthreads();
    if (kw == 0) {
        float r = red[0][j] + red[1][j] + red[2][j] + red[3][j] + s_b2[j];
        rowC[j] = r;
        transHs[s * DD + j] = r;
    }
    __syncthreads();
    float a3 = 0.f;
#pragma unroll 16
    for (int d = kw * 64; d < kw * 64 + 64; ++d)
        a3 = fmaf(rowC[d], w_w1[(256 + d) * DD + j], a3);
    red[kw][j] = a3;
    __syncthreads();
    if (kw == 0)
        S1b[s * DD + j] = red[0][j] + red[1][j] + red[2][j] + red[3][j] + w_b1[j];
}

// Two pack jobs:
//  [0,256)    Apack: bf16(Hx) in A-fragment order
//  [256,2304) Bs:    bf16(W1a + m_s*C) in B-fragment order, per slot
__global__ __launch_bounds__(256) void
k_pack_all(const float* __restrict__ Hx, const float* __restrict__ w_w1,
           const float* __restrict__ transHs, unsigned* __restrict__ Apack,
           unsigned* __restrict__ Bs) {
    const int bid = blockIdx.x;
    if (bid < 256) {
        int idx = bid * 256 + threadIdx.x;          // 0..65535
        int lane = idx & 63, ks = (idx >> 6) & 7, MT = idx >> 9;
        int t  = MT * 16 + (lane & 15);
        int k0 = ks * 32 + (lane >> 4) * 8;
        const float* src = Hx + t * DD + k0;
        float4 x0 = *(const float4*)src;
        float4 x1 = *(const float4*)(src + 4);
        unsigned p[4];
        p[0] = pack_bf16(x0.x, x0.y);
        p[1] = pack_bf16(x0.z, x0.w);
        p[2] = pack_bf16(x1.x, x1.y);
        p[3] = pack_bf16(x1.z, x1.w);
        *(u32x4*)(Apack + idx * 4) = *(const u32x4*)p;
    } else {
        int b2 = bid - 256;
        int s = b2 >> 5;
        int idx = (b2 & 31) * 256 + threadIdx.x;    // 0..8191
        int lane = idx & 63, ks = (idx >> 6) & 7, nt = idx >> 9;
        int j  = nt * 16 + (lane & 15);
        int k0 = ks * 32 + (lane >> 4) * 8;
        const float* C   = w_w1 + 512 * DD;
        const float* W1a = w_w1;
        const float* ms  = transHs + s * DD;
        unsigned p[4];
#pragma unroll
        for (int e = 0; e < 4; ++e) {
            int k = k0 + 2 * e;
            float f0 = W1a[k * DD + j] + ms[k] * C[k * DD + j];
            float f1 = W1a[(k + 1) * DD + j] + ms[k + 1] * C[(k + 1) * DD + j];
            p[e] = pack_bf16(f0, f1);
        }
        *(u32x4*)(Bs + (s * 8192 + idx) * 4) = *(const u32x4*)p;
    }
}

// atten[t][s] = w2 . relu( A@Bs[s] + S1b[s] ) + b2
// grid=(16,64) block=256. A-tile (64KB) staged once in LDS via global_load_lds;
// B streamed per-wave (disjoint nt slices -> no duplication).
__global__ __launch_bounds__(256, 2) void
k_main_mfma(const unsigned* __restrict__ Apack, const unsigned* __restrict__ Bs,
            const float* __restrict__ S1b, const float* __restrict__ w2,
            const float* __restrict__ w_b2, float* __restrict__ atten) {
    __shared__ unsigned Albs[16384];            // 64 KB; reused as reduce scratch
    const int s  = blockIdx.y;
    const int t0 = blockIdx.x * 128;
    const int tid = threadIdx.x;
    const int w = tid >> 6, l = tid & 63;
    const int lrow = l & 15, lg = l >> 4;
    const unsigned* Asrc = Apack + blockIdx.x * 16384;
    const unsigned* Bsl  = Bs + s * 32768;

    // stage A: 64 chunks of 1KB; wave w issues chunks w*16..w*16+15
#pragma unroll
    for (int i = 0; i < 16; ++i) {
        int chunk = w * 16 + i;
        __builtin_amdgcn_global_load_lds((glb_u32*)(Asrc + chunk * 256 + l * 4),
                                         (lds_u32*)(Albs + chunk * 256), 16, 0, 0);
    }
    __syncthreads();

    f32x4 acc[8][4] = {};
    for (int ks = 0; ks < 8; ++ks) {
        bf16x8 af[8];
#pragma unroll
        for (int mt = 0; mt < 8; ++mt)
            af[mt] = *(const bf16x8*)((const char*)Albs + ((mt * 8 + ks) * 64 + l) * 16);
#pragma unroll
        for (int nt = 0; nt < 4; ++nt) {
            const bf16x8 bf = *(const bf16x8*)(Bsl + (((w * 4 + nt) * 8 + ks) * 64 + l) * 4);
#pragma unroll
            for (int mt = 0; mt < 8; ++mt)
                acc[mt][nt] = __builtin_amdgcn_mfma_f32_16x16x32_bf16(af[mt], bf, acc[mt][nt], 0, 0, 0);
        }
    }
    __syncthreads();                            // A reads done before LDS reuse

    float* attp = (float*)Albs;                 // [4][128]
    float s1[4], w2v[4];
#pragma unroll
    for (int nt = 0; nt < 4; ++nt) {
        int jn = (w * 4 + nt) * 16 + lrow;
        s1[nt]  = S1b[s * DD + jn];
        w2v[nt] = w2[jn];
    }
#pragma unroll
    for (int mt = 0; mt < 8; ++mt) {
#pragma unroll
        for (int i = 0; i < 4; ++i) {
            float p = 0.f;
#pragma unroll
            for (int nt = 0; nt < 4; ++nt) {
                float h = fmaxf(acc[mt][nt][i] + s1[nt], 0.f);
                p = fmaf(h, w2v[nt], p);
            }
            p += __shfl_xor(p, 1);
            p += __shfl_xor(p, 2);
            p += __shfl_xor(p, 4);
            p += __shfl_xor(p, 8);
            if (lrow == 0) attp[w * 128 + mt * 16 + lg * 4 + i] = p;
        }
    }
    __syncthreads();
    if (tid < 128) {
        float r = attp[tid] + attp[128 + tid] + attp[256 + tid] + attp[384 + tid] + w_b2[0];
        atten[(t0 + tid) * SS + s] = r;
    }
}

// softmax over slots + G = score@transHs + output assembly. grid=(512) block=(256)
__global__ __launch_bounds__(256) void
k_out(const float* __restrict__ Hx, const float* __restrict__ m,
      const float* __restrict__ atten, float* __restrict__ outU,
      float* __restrict__ outA) {
    int wave = threadIdx.x >> 6, lane = threadIdx.x & 63;
    int t = blockIdx.x * 4 + wave;
    float a = atten[t * SS + lane];
    float mx = a;
#pragma unroll
    for (int off = 32; off; off >>= 1) mx = fmaxf(mx, __shfl_xor(mx, off));
    float e = __expf(a - mx);
    float sum = e;
#pragma unroll
    for (int off = 32; off; off >>= 1) sum += __shfl_xor(sum, off);
    float p = e / sum;
    outA[t * SS + lane] = p;
    float gacc[4] = {};
    for (int s = 0; s < SS; ++s) {
        float ps = __shfl(p, s);
#pragma unroll
        for (int q = 0; q < 4; ++q)
            gacc[q] = fmaf(ps, m[s * DD + lane + 64 * q], gacc[q]);
    }
#pragma unroll
    for (int q = 0; q < 4; ++q) {
        int j = lane + 64 * q;
        float x = Hx[t * DD + j];
        outU[t * 2 * DD + j] = x;
        outU[t * 2 * DD + DD + j] = x + gacc[q];
    }
}

extern "C" void kernel_launch(void* const* d_in, const int* in_sizes, int n_in,
                              void* d_out, int out_size, void* d_ws, size_t ws_size,
                              hipStream_t stream) {
    const float* Hx   = (const float*)d_in[0];
    const float* Hs   = (const float*)d_in[1];
    const float* bn_g = (const float*)d_in[2];
    const float* bn_b = (const float*)d_in[3];
    const float* s_w1 = (const float*)d_in[4];
    const float* s_b1 = (const float*)d_in[5];
    const float* s_w2 = (const float*)d_in[6];
    const float* s_b2 = (const float*)d_in[7];
    const float* w_w1 = (const float*)d_in[8];
    const float* w_b1 = (const float*)d_in[9];
    const float* w_w2 = (const float*)d_in[10];
    const float* w_b2 = (const float*)d_in[11];

    float* ws      = (float*)d_ws;
    float* transHs = ws;                        // 16384 f
    float* S1b     = ws + 16384;                // 16384 f
    float* atten   = ws + 32768;                // 131072 f
    unsigned* Apack = (unsigned*)(ws + 163840); // 262144 u32 (1 MB)
    unsigned* Bs    = Apack + 262144;           // 2097152 u32 (8 MB)

    float* outU = (float*)d_out;                // [2048][512]
    float* outA = outU + BT * 2 * DD;           // [2048][64]

    k_prep2<<<SS, 1024, 0, stream>>>(Hs, bn_g, bn_b, s_w1, s_b1, s_w2, s_b2,
                                     w_w1, w_b1, transHs, S1b);
    k_pack_all<<<2304, 256, 0, stream>>>(Hx, w_w1, transHs, Apack, Bs);
    dim3 gmain(BT / 128, SS);
    k_main_mfma<<<gmain, 256, 0, stream>>>(Apack, Bs, S1b, w_w2, w_b2, atten);
    k_out<<<BT / 4, 256, 0, stream>>>(Hx, transHs, atten, outU, outA);
}